// Round 5
// baseline (139.700 us; speedup 1.0000x reference)
//
#include <hip/hip_runtime.h>
#include <hip/hip_bf16.h>

// n=16,c=256,h=w=64 -> 4096 independent 64x64 tiles.
// A = softmax_h(X^T); Xn = rowwise LN(X) (unbiased std, eps on std);
// node = A@Xn; out = relu(node@W).
// MFMA 32x32x16_bf16. A = hi only (A in [0,1], rows sum to 1);
// Xn, W, node = hi/lo bf16 pairs. 20 MFMAs/wave.
// W fragments live in REGISTERS (hoisted global loads, L2-resident),
// LDS = 24KB -> 6 blocks/CU.

typedef __attribute__((ext_vector_type(8)))  short  s16x8;   // MFMA A/B frag
typedef __attribute__((ext_vector_type(16))) float  f32x16;  // MFMA C/D frag
typedef __attribute__((ext_vector_type(8)))  unsigned short us8;

__device__ __forceinline__ unsigned short f2bf(float x) {
    __hip_bfloat16 b = __float2bfloat16(x);
    return __builtin_bit_cast(unsigned short, b);
}
__device__ __forceinline__ float bf2f(unsigned short h) {
    unsigned u = ((unsigned)h) << 16;
    return __builtin_bit_cast(float, u);
}
// swizzle: balances the b128 MFMA reads (8 quads across banks) AND the
// strided b16 LN writes (rows {i,16+i,32+i,48+i} -> 4 distinct sw values).
__device__ __forceinline__ int swz(int row) {
    return ((row & 7) ^ ((row >> 3) & 7)) << 3;
}
__device__ __forceinline__ int swidx(int row, int k) {
    return row * 64 + (k ^ swz(row));
}

// one-time W -> WT[j][k] bf16 hi/lo into ws, LINEAR layout (register frags)
__global__ void prep_w(const float* __restrict__ Wg, unsigned short* __restrict__ ws) {
    const int gid = blockIdx.x * 256 + threadIdx.x;  // 0..4095
    const int j = gid & 63;          // col of W
    const int k = gid >> 6;          // row of W
    const float x = Wg[k * 64 + j];  // coalesced over j
    const unsigned short hh = f2bf(x);
    const unsigned short ll = f2bf(x - bf2f(hh));
    ws[j * 64 + k] = hh;             // WT[j][k]
    ws[4096 + j * 64 + k] = ll;
}

__global__ __launch_bounds__(256, 6)
void gnn_mfma(const float* __restrict__ X, const unsigned short* __restrict__ Wp,
              const float* __restrict__ a2, const float* __restrict__ b2,
              float* __restrict__ out)
{
    // 8KB + 16KB = 24KB -> 6 blocks/CU
    __shared__ __align__(16) unsigned short bufA[64 * 64];     // A hi; later node hi
    __shared__ __align__(16) unsigned short bufX[2][64 * 64];  // XnT hi/lo; [0] later node lo

    const int tid = threadIdx.x;
    const int b   = blockIdx.x;
    const float* xb = X + (size_t)b * 4096;

    const int wid  = tid >> 6;
    const int lane = tid & 63;
    const int r    = lane & 31;
    const int hl   = lane >> 5;
    const int R = (wid & 1) * 32;     // output row base (w1)
    const int C = (wid >> 1) * 32;    // output col base (w2 / j)
    const int rowA = R + r;           // A / node row
    const int rowB = C + r;           // XnT row / WT row (j)
    const int swA = swz(rowA);
    const int swB = swz(rowB);

    // ---- hoisted W fragment loads (L2-resident; latency hides under SM/LN) ----
    us8 wh0, wh1, wh2, wh3, wl0, wl1, wl2, wl3;
    {
        const us8* ph = (const us8*)&Wp[rowB * 64 + 8 * hl];
        const us8* pl = (const us8*)&Wp[4096 + rowB * 64 + 8 * hl];
        wh0 = ph[0]; wh1 = ph[2]; wh2 = ph[4]; wh3 = ph[6];
        wl0 = pl[0]; wl1 = pl[2]; wl2 = pl[4]; wl3 = pl[6];
    }

    // ---- phase 1: column softmax -> A[wi][h] (hi only, swizzled) ----
    {
        const int wi = tid >> 2;            // 0..63
        const int h0 = (tid & 3) << 4;      // 0,16,32,48
        float v[16];
        #pragma unroll
        for (int i = 0; i < 16; ++i) v[i] = xb[(h0 + i) * 64 + wi];
        float m = v[0];
        #pragma unroll
        for (int i = 1; i < 16; ++i) m = fmaxf(m, v[i]);
        m = fmaxf(m, __shfl_xor(m, 1));
        m = fmaxf(m, __shfl_xor(m, 2));
        float s = 0.f;
        #pragma unroll
        for (int i = 0; i < 16; ++i) { v[i] = __expf(v[i] - m); s += v[i]; }
        s += __shfl_xor(s, 1);
        s += __shfl_xor(s, 2);
        const float inv = 1.0f / s;
        us8 hv0, hv1;
        #pragma unroll
        for (int i = 0; i < 8; ++i) hv0[i] = f2bf(v[i] * inv);
        #pragma unroll
        for (int i = 0; i < 8; ++i) hv1[i] = f2bf(v[8 + i] * inv);
        const int sw = swz(wi);
        *(us8*)&bufA[wi * 64 + (h0 ^ sw)]       = hv0;
        *(us8*)&bufA[wi * 64 + ((h0 + 8) ^ sw)] = hv1;
    }

    // ---- phase 2: row layernorm -> XnT[c][h] hi/lo (transposed b16 writes) ----
    {
        const int h  = tid >> 2;            // 0..63 (X row)
        const int c0 = (tid & 3) << 4;      // 0,16,32,48
        float x[16];
        #pragma unroll
        for (int i = 0; i < 4; ++i) {
            float4 t = *(const float4*)&xb[h * 64 + c0 + 4 * i];
            x[4 * i] = t.x; x[4 * i + 1] = t.y; x[4 * i + 2] = t.z; x[4 * i + 3] = t.w;
        }
        float s = 0.f, sq = 0.f;
        #pragma unroll
        for (int i = 0; i < 16; ++i) { s += x[i]; sq += x[i] * x[i]; }
        s  += __shfl_xor(s, 1);  s  += __shfl_xor(s, 2);
        sq += __shfl_xor(sq, 1); sq += __shfl_xor(sq, 2);
        const float mean = s * (1.0f / 64.0f);
        float var = (sq - 64.0f * mean * mean) * (1.0f / 63.0f);
        var = fmaxf(var, 0.0f);
        const float invstd = 1.0f / (sqrtf(var) + 1e-6f);
        #pragma unroll
        for (int i = 0; i < 4; ++i) {           // chunked: short live ranges
            float4 ta = *(const float4*)&a2[c0 + 4 * i];
            float4 tb = *(const float4*)&b2[c0 + 4 * i];
            const float aa[4] = {ta.x, ta.y, ta.z, ta.w};
            const float bb[4] = {tb.x, tb.y, tb.z, tb.w};
            #pragma unroll
            for (int e = 0; e < 4; ++e) {
                const int c = c0 + 4 * i + e;
                const float xn = aa[e] * (x[4 * i + e] - mean) * invstd + bb[e];
                const unsigned short hh = f2bf(xn);
                const int idx = swidx(c, h);
                bufX[0][idx] = hh;
                bufX[1][idx] = f2bf(xn - bf2f(hh));
            }
        }
    }
    __syncthreads();

    // ---- matmul 1: node = A @ Xn (wave -> one 32x32 tile), 8 MFMAs ----
    f32x16 acc;
    #pragma unroll
    for (int i = 0; i < 16; ++i) acc[i] = 0.f;

    #pragma unroll
    for (int t = 0; t < 4; ++t) {
        const int k0 = 16 * t + 8 * hl;
        s16x8 aH = *(const s16x8*)&bufA[rowA * 64 + (k0 ^ swA)];
        s16x8 bH = *(const s16x8*)&bufX[0][rowB * 64 + (k0 ^ swB)];
        s16x8 bL = *(const s16x8*)&bufX[1][rowB * 64 + (k0 ^ swB)];
        acc = __builtin_amdgcn_mfma_f32_32x32x16_bf16(aH, bH, acc, 0, 0, 0);
        acc = __builtin_amdgcn_mfma_f32_32x32x16_bf16(aH, bL, acc, 0, 0, 0);
    }
    __syncthreads();   // all mm1 reads of bufA/bufX done

    // node[w1][w2] hi -> bufA, lo -> bufX[0]
    #pragma unroll
    for (int g = 0; g < 16; ++g) {
        const int w1 = R + (g & 3) + 8 * (g >> 2) + 4 * hl;  // C/D row map (m74/m101)
        const float xv = acc[g];
        const unsigned short hh = f2bf(xv);
        const int idx = swidx(w1, C + r);
        bufA[idx]    = hh;
        bufX[0][idx] = f2bf(xv - bf2f(hh));
    }
    __syncthreads();

    // ---- matmul 2: out = relu(node @ W), 12 MFMAs, W from registers ----
    f32x16 acc2;
    #pragma unroll
    for (int i = 0; i < 16; ++i) acc2[i] = 0.f;

    #pragma unroll
    for (int t = 0; t < 4; ++t) {
        const int k0 = 16 * t + 8 * hl;
        s16x8 nH = *(const s16x8*)&bufA[rowA * 64 + (k0 ^ swA)];
        s16x8 nL = *(const s16x8*)&bufX[0][rowA * 64 + (k0 ^ swA)];
        const s16x8 wH = __builtin_bit_cast(s16x8, t == 0 ? wh0 : t == 1 ? wh1 : t == 2 ? wh2 : wh3);
        const s16x8 wL = __builtin_bit_cast(s16x8, t == 0 ? wl0 : t == 1 ? wl1 : t == 2 ? wl2 : wl3);
        acc2 = __builtin_amdgcn_mfma_f32_32x32x16_bf16(nH, wH, acc2, 0, 0, 0);
        acc2 = __builtin_amdgcn_mfma_f32_32x32x16_bf16(nH, wL, acc2, 0, 0, 0);
        acc2 = __builtin_amdgcn_mfma_f32_32x32x16_bf16(nL, wH, acc2, 0, 0, 0);
    }

    float* ob = out + (size_t)b * 4096;
    #pragma unroll
    for (int g = 0; g < 16; ++g) {
        const int w1 = R + (g & 3) + 8 * (g >> 2) + 4 * hl;
        ob[w1 * 64 + C + r] = fmaxf(acc2[g], 0.f);
    }
}

extern "C" void kernel_launch(void* const* d_in, const int* in_sizes, int n_in,
                              void* d_out, int out_size, void* d_ws, size_t ws_size,
                              hipStream_t stream) {
    const float* X  = (const float*)d_in[0];
    const float* W  = (const float*)d_in[1];
    const float* a2 = (const float*)d_in[2];
    const float* b2 = (const float*)d_in[3];
    float* out = (float*)d_out;
    unsigned short* wp = (unsigned short*)d_ws;   // 16KB: WT hi[4096] + lo[4096]
    prep_w<<<16, 256, 0, stream>>>(W, wp);
    gnn_mfma<<<4096, 256, 0, stream>>>(X, wp, a2, b2, out);
}

// Round 7
// 130.820 us; speedup vs baseline: 1.0679x; 1.0679x over previous
//
#include <hip/hip_runtime.h>
#include <hip/hip_bf16.h>

// n=16,c=256,h=w=64 -> 4096 independent 64x64 tiles.
// A = softmax_h(X^T); Xn = rowwise LN(X) (unbiased std, eps on std);
// node = A@Xn; out = relu(node@W).
// MFMA 32x32x16_bf16. A = hi only; Xn, W, node = hi/lo bf16 pairs.
// R6: 2 tiles per block, phases interleaved -> half the barriers per tile,
// 2x independent work per barrier segment. W fragments in registers, loaded
// right before the first barrier (short live range -> compiler keeps them).

typedef __attribute__((ext_vector_type(8)))  short  s16x8;   // MFMA A/B frag
typedef __attribute__((ext_vector_type(16))) float  f32x16;  // MFMA C/D frag
typedef __attribute__((ext_vector_type(8)))  unsigned short us8;

__device__ __forceinline__ unsigned short f2bf(float x) {
    __hip_bfloat16 b = __float2bfloat16(x);
    return __builtin_bit_cast(unsigned short, b);
}
__device__ __forceinline__ float bf2f(unsigned short h) {
    unsigned u = ((unsigned)h) << 16;
    return __builtin_bit_cast(float, u);
}
// swizzle: balances b128 MFMA reads AND strided b16 LN/node writes
__device__ __forceinline__ int swz(int row) {
    return ((row & 7) ^ ((row >> 3) & 7)) << 3;
}
__device__ __forceinline__ int swidx(int row, int k) {
    return row * 64 + (k ^ swz(row));
}

// one-time W -> WT[j][k] bf16 hi/lo into ws, LINEAR layout (register frags)
__global__ void prep_w(const float* __restrict__ Wg, unsigned short* __restrict__ ws) {
    const int gid = blockIdx.x * 256 + threadIdx.x;  // 0..4095
    const int j = gid & 63;          // col of W
    const int k = gid >> 6;          // row of W
    const float x = Wg[k * 64 + j];  // coalesced over j
    const unsigned short hh = f2bf(x);
    ws[j * 64 + k] = hh;             // WT[j][k]
    ws[4096 + j * 64 + k] = f2bf(x - bf2f(hh));
}

__global__ __launch_bounds__(256, 3)
void gnn_mfma(const float* __restrict__ X, const unsigned short* __restrict__ Wp,
              const float* __restrict__ a2, const float* __restrict__ b2,
              float* __restrict__ out)
{
    // 6 x 8KB = 48KB -> 3 blocks/CU
    __shared__ __align__(16) unsigned short bufA [2][64 * 64]; // A hi; later node hi
    __shared__ __align__(16) unsigned short bufXh[2][64 * 64]; // XnT hi
    __shared__ __align__(16) unsigned short bufXl[2][64 * 64]; // XnT lo; later node lo

    const int tid = threadIdx.x;
    const int b   = blockIdx.x;             // 0..2047, owns tiles 2b, 2b+1

    const int wid  = tid >> 6;
    const int lane = tid & 63;
    const int r    = lane & 31;
    const int hl   = lane >> 5;
    const int R = (wid & 1) * 32;           // output row base (w1)
    const int C = (wid >> 1) * 32;          // output col base (w2 / j)
    const int rowA = R + r;                 // A / node row
    const int rowB = C + r;                 // XnT row / WT row (j)
    const int swA = swz(rowA);
    const int swB = swz(rowB);

    // ---- a2/b2 loaded once, shared by both tiles' LN ----
    const int h_  = tid >> 2;               // 0..63 (X row for LN)
    const int c0_ = (tid & 3) << 4;         // 0,16,32,48
    float av[16], bv[16];
    #pragma unroll
    for (int i = 0; i < 4; ++i) {
        float4 ta = *(const float4*)&a2[c0_ + 4 * i];
        float4 tb = *(const float4*)&b2[c0_ + 4 * i];
        av[4*i] = ta.x; av[4*i+1] = ta.y; av[4*i+2] = ta.z; av[4*i+3] = ta.w;
        bv[4*i] = tb.x; bv[4*i+1] = tb.y; bv[4*i+2] = tb.z; bv[4*i+3] = tb.w;
    }

    // ---- seg1: softmax + layernorm for both tiles (independent work) ----
    auto seg1 = [&](const float* xb, unsigned short* bA,
                    unsigned short* bXh, unsigned short* bXl) {
        // column softmax -> A[wi][h] (hi only, swizzled)
        {
            const int wi = tid >> 2;
            const int h0 = (tid & 3) << 4;
            float v[16];
            #pragma unroll
            for (int i = 0; i < 16; ++i) v[i] = xb[(h0 + i) * 64 + wi];
            float m = v[0];
            #pragma unroll
            for (int i = 1; i < 16; ++i) m = fmaxf(m, v[i]);
            m = fmaxf(m, __shfl_xor(m, 1));
            m = fmaxf(m, __shfl_xor(m, 2));
            float s = 0.f;
            #pragma unroll
            for (int i = 0; i < 16; ++i) { v[i] = __expf(v[i] - m); s += v[i]; }
            s += __shfl_xor(s, 1);
            s += __shfl_xor(s, 2);
            const float inv = 1.0f / s;
            us8 hv0, hv1;
            #pragma unroll
            for (int i = 0; i < 8; ++i) hv0[i] = f2bf(v[i] * inv);
            #pragma unroll
            for (int i = 0; i < 8; ++i) hv1[i] = f2bf(v[8 + i] * inv);
            const int sw = swz(wi);
            *(us8*)&bA[wi * 64 + (h0 ^ sw)]       = hv0;
            *(us8*)&bA[wi * 64 + ((h0 + 8) ^ sw)] = hv1;
        }
        // row layernorm -> XnT[c][h] hi/lo (transposed b16 writes, 2-way free)
        {
            float x[16];
            #pragma unroll
            for (int i = 0; i < 4; ++i) {
                float4 t = *(const float4*)&xb[h_ * 64 + c0_ + 4 * i];
                x[4*i] = t.x; x[4*i+1] = t.y; x[4*i+2] = t.z; x[4*i+3] = t.w;
            }
            float s = 0.f, sq = 0.f;
            #pragma unroll
            for (int i = 0; i < 16; ++i) { s += x[i]; sq += x[i] * x[i]; }
            s  += __shfl_xor(s, 1);  s  += __shfl_xor(s, 2);
            sq += __shfl_xor(sq, 1); sq += __shfl_xor(sq, 2);
            const float mean = s * (1.0f / 64.0f);
            float var = (sq - 64.0f * mean * mean) * (1.0f / 63.0f);
            var = fmaxf(var, 0.0f);
            const float invstd = 1.0f / (sqrtf(var) + 1e-6f);
            #pragma unroll
            for (int i = 0; i < 16; ++i) {
                const float xn = av[i] * (x[i] - mean) * invstd + bv[i];
                const unsigned short hh = f2bf(xn);
                const int idx = swidx(c0_ + i, h_);
                bXh[idx] = hh;
                bXl[idx] = f2bf(xn - bf2f(hh));
            }
        }
    };

    const float* xb0 = X + (size_t)(2 * b)     * 4096;
    const float* xb1 = X + (size_t)(2 * b + 1) * 4096;
    seg1(xb0, bufA[0], bufXh[0], bufXl[0]);
    seg1(xb1, bufA[1], bufXh[1], bufXl[1]);

    // ---- W fragment loads (L2-resident): short live range, reused by both tiles
    us8 wh0, wh1, wh2, wh3, wl0, wl1, wl2, wl3;
    {
        const us8* ph = (const us8*)&Wp[rowB * 64 + 8 * hl];
        const us8* pl = (const us8*)&Wp[4096 + rowB * 64 + 8 * hl];
        wh0 = ph[0]; wh1 = ph[2]; wh2 = ph[4]; wh3 = ph[6];
        wl0 = pl[0]; wl1 = pl[2]; wl2 = pl[4]; wl3 = pl[6];
    }
    __syncthreads();

    // ---- mm1 both tiles: node = A @ Xn, 8 MFMAs each ----
    auto mm1 = [&](const unsigned short* bA, const unsigned short* bXh,
                   const unsigned short* bXl) -> f32x16 {
        f32x16 acc;
        #pragma unroll
        for (int i = 0; i < 16; ++i) acc[i] = 0.f;
        #pragma unroll
        for (int t = 0; t < 4; ++t) {
            const int k0 = 16 * t + 8 * hl;
            s16x8 aH = *(const s16x8*)&bA [rowA * 64 + (k0 ^ swA)];
            s16x8 bH = *(const s16x8*)&bXh[rowB * 64 + (k0 ^ swB)];
            s16x8 bL = *(const s16x8*)&bXl[rowB * 64 + (k0 ^ swB)];
            acc = __builtin_amdgcn_mfma_f32_32x32x16_bf16(aH, bH, acc, 0, 0, 0);
            acc = __builtin_amdgcn_mfma_f32_32x32x16_bf16(aH, bL, acc, 0, 0, 0);
        }
        return acc;
    };
    f32x16 acc0 = mm1(bufA[0], bufXh[0], bufXl[0]);
    f32x16 acc1 = mm1(bufA[1], bufXh[1], bufXl[1]);
    __syncthreads();   // all mm1 reads done before node overwrites

    // node[w1][w2]: hi -> bufA, lo -> bufXl (2-way bank, free)
    #pragma unroll
    for (int g = 0; g < 16; ++g) {
        const int w1 = R + (g & 3) + 8 * (g >> 2) + 4 * hl;  // C/D row map
        const int idx = swidx(w1, C + r);
        const float x0 = acc0[g];
        const unsigned short h0 = f2bf(x0);
        bufA[0][idx]  = h0;
        bufXl[0][idx] = f2bf(x0 - bf2f(h0));
        const float x1 = acc1[g];
        const unsigned short h1 = f2bf(x1);
        bufA[1][idx]  = h1;
        bufXl[1][idx] = f2bf(x1 - bf2f(h1));
    }
    __syncthreads();

    // ---- mm2 both tiles: out = relu(node @ W), 12 MFMAs each, W in regs ----
    auto mm2 = [&](const unsigned short* bNh, const unsigned short* bNl) -> f32x16 {
        f32x16 acc;
        #pragma unroll
        for (int i = 0; i < 16; ++i) acc[i] = 0.f;
        #pragma unroll
        for (int t = 0; t < 4; ++t) {
            const int k0 = 16 * t + 8 * hl;
            s16x8 nH = *(const s16x8*)&bNh[rowA * 64 + (k0 ^ swA)];
            s16x8 nL = *(const s16x8*)&bNl[rowA * 64 + (k0 ^ swA)];
            const s16x8 wH = __builtin_bit_cast(s16x8, t == 0 ? wh0 : t == 1 ? wh1 : t == 2 ? wh2 : wh3);
            const s16x8 wL = __builtin_bit_cast(s16x8, t == 0 ? wl0 : t == 1 ? wl1 : t == 2 ? wl2 : wl3);
            acc = __builtin_amdgcn_mfma_f32_32x32x16_bf16(nH, wH, acc, 0, 0, 0);
            acc = __builtin_amdgcn_mfma_f32_32x32x16_bf16(nH, wL, acc, 0, 0, 0);
            acc = __builtin_amdgcn_mfma_f32_32x32x16_bf16(nL, wH, acc, 0, 0, 0);
        }
        return acc;
    };
    f32x16 o0 = mm2(bufA[0], bufXl[0]);
    f32x16 o1 = mm2(bufA[1], bufXl[1]);

    float* ob0 = out + (size_t)(2 * b)     * 4096;
    float* ob1 = out + (size_t)(2 * b + 1) * 4096;
    #pragma unroll
    for (int g = 0; g < 16; ++g) {
        const int w1 = R + (g & 3) + 8 * (g >> 2) + 4 * hl;
        ob0[w1 * 64 + C + r] = fmaxf(o0[g], 0.f);
        ob1[w1 * 64 + C + r] = fmaxf(o1[g], 0.f);
    }
}

extern "C" void kernel_launch(void* const* d_in, const int* in_sizes, int n_in,
                              void* d_out, int out_size, void* d_ws, size_t ws_size,
                              hipStream_t stream) {
    const float* X  = (const float*)d_in[0];
    const float* W  = (const float*)d_in[1];
    const float* a2 = (const float*)d_in[2];
    const float* b2 = (const float*)d_in[3];
    float* out = (float*)d_out;
    unsigned short* wp = (unsigned short*)d_ws;   // 16KB: WT hi[4096] + lo[4096]
    prep_w<<<16, 256, 0, stream>>>(W, wp);
    gnn_mfma<<<2048, 256, 0, stream>>>(X, wp, a2, b2, out);
}